// Round 6
// baseline (331.090 us; speedup 1.0000x reference)
//
#include <hip/hip_runtime.h>

// Causal self-attention fwd: x(4,2048,1024)fp32, W_qkv(1024,3072), W_proj(1024,1024)
// Pipeline: [transpose W->bf16] [x->bf16] [GEMM1 qkv + fused V-transpose] [RoPE q,k]
//           [flash attn] [GEMM2 out]
// R5: attn 32q/wave, Q pre-scaled (exp2), GEMM BK=64 swizzled.
// R6: attn barrier-free — K/V fragments read per-wave straight from global (L2),
//     LDS holds only per-wave P (16KB/block). No __syncthreads at all; each wave
//     breaks at its own causal limit. launch_bounds(256,3) -> 3+ waves/SIMD.

#define BATCH 4
#define SEQ   2048
#define DM    1024
#define NH    16
#define HD    64
#define QKV_W 3072

typedef short bf16x8 __attribute__((ext_vector_type(8)));
typedef float f32x4  __attribute__((ext_vector_type(4)));
typedef unsigned short bf16_t;

__device__ __forceinline__ unsigned short f2bf(float f) {
  unsigned u = __float_as_uint(f);
  u += 0x7fffu + ((u >> 16) & 1u);   // round-to-nearest-even
  return (unsigned short)(u >> 16);
}
__device__ __forceinline__ float bf2f(unsigned short s) {
  return __uint_as_float((unsigned)s << 16);
}
// async global->LDS, 16B per lane; LDS dest is wave-uniform base + lane*16
__device__ __forceinline__ void gld16(const void* g, void* l) {
  __builtin_amdgcn_global_load_lds(
      (const __attribute__((address_space(1))) unsigned int*)g,
      (__attribute__((address_space(3))) unsigned int*)l, 16, 0, 0);
}

// ---------------- W[K][N] fp32 -> Wt[N][K] bf16 ----------------
__global__ __launch_bounds__(256) void k_transpose(const float* __restrict__ W,
                                                   bf16_t* __restrict__ Wt,
                                                   int K, int N) {
  __shared__ float tile[32][33];
  const int tx = threadIdx.x, ty = threadIdx.y;   // (32,8)
  const int n0 = blockIdx.x * 32, k0 = blockIdx.y * 32;
#pragma unroll
  for (int j = 0; j < 4; ++j)
    tile[ty + j * 8][tx] = W[(size_t)(k0 + ty + j * 8) * N + n0 + tx];
  __syncthreads();
#pragma unroll
  for (int j = 0; j < 4; ++j)
    Wt[(size_t)(n0 + ty + j * 8) * K + k0 + tx] = f2bf(tile[tx][ty + j * 8]);
}

// ---------------- fp32 -> bf16 elementwise ----------------
__global__ __launch_bounds__(256) void k_cvt(const float* __restrict__ x,
                                             bf16_t* __restrict__ xb) {
  const int i = (blockIdx.x * 256 + threadIdx.x) * 4;
  float4 v = *(const float4*)(x + i);
  unsigned lo = (unsigned)f2bf(v.x) | ((unsigned)f2bf(v.y) << 16);
  unsigned hi = (unsigned)f2bf(v.z) | ((unsigned)f2bf(v.w) << 16);
  *(uint2*)(xb + i) = make_uint2(lo, hi);
}

// ---------------- RoPE in place on q,k sections of qkv ----------------
__global__ __launch_bounds__(256) void k_rope(bf16_t* __restrict__ qkv) {
  const int t = blockIdx.x * 256 + threadIdx.x;
  const int i = t & 31;            // freq index 0..31
  const int h = (t >> 5) & 15;     // head
  const int s = (t >> 9) & 2047;   // position
  const int b = t >> 20;
  const float inv = __expf((float)i * -0.28782313662425575f); // -ln(10000)/32
  float sn, cs;
  sincosf((float)s * inv, &sn, &cs);
  size_t base = ((size_t)(b * SEQ + s)) * QKV_W + h * HD + 2 * i;
#pragma unroll
  for (int part = 0; part < 2; ++part) {      // q then k
    unsigned u = *(unsigned*)(qkv + base + part * DM);
    float e = bf2f((unsigned short)(u & 0xffffu));
    float o = bf2f((unsigned short)(u >> 16));
    unsigned short e2 = f2bf(e * cs - o * sn);
    unsigned short o2 = f2bf(e * sn + o * cs);
    *(unsigned*)(qkv + base + part * DM) = (unsigned)e2 | ((unsigned)o2 << 16);
  }
}

// ---------------- bf16 GEMM: C = A[M][K] * Bt[N][K]^T ----------------
// 128x128 tile, BK=64 (16 iters @ K=1024), XOR-swizzled [128][64] LDS.
// MODE 0: fp32 C. MODE 1: qkv epilogue — cols<2048 (Q,K) bf16 row-major;
// cols>=2048 (V) -> vt[b][h][d][s] packed ushort4.
template<int MODE>
__global__ __launch_bounds__(256) void k_gemm(const bf16_t* __restrict__ A,
                                              const bf16_t* __restrict__ Bt,
                                              void* __restrict__ Cout,
                                              bf16_t* __restrict__ vt,
                                              int M, int N, int K) {
  __shared__ __align__(16) short As[128 * 64];
  __shared__ __align__(16) short Bs[128 * 64];
  const int tid = threadIdx.x;
  const int wave = tid >> 6, lane = tid & 63;
  const int quad = lane >> 4, l16 = lane & 15;
  const int wm = (wave >> 1) * 64, wn = (wave & 1) * 64;
  const int bm = blockIdx.y * 128, bn = blockIdx.x * 128;

  f32x4 acc[4][4];
#pragma unroll
  for (int i = 0; i < 4; ++i)
#pragma unroll
    for (int j = 0; j < 4; ++j) acc[i][j] = f32x4{0.f, 0.f, 0.f, 0.f};

  const int srow = tid >> 3;                       // 0..31
  const int sg   = (tid & 7) ^ (srow & 7);         // swizzled source granule
  const bf16_t* Ap = A  + (size_t)(bm + srow) * K + sg * 8;
  const bf16_t* Bp = Bt + (size_t)(bn + srow) * K + sg * 8;
  short* Ad = As + tid * 8;
  short* Bd = Bs + tid * 8;

  for (int k0 = 0; k0 < K; k0 += 64) {
    __syncthreads();
#pragma unroll
    for (int pp = 0; pp < 4; ++pp) {
      gld16(Ap + (size_t)(pp * 32) * K + k0, Ad + pp * 2048);
      gld16(Bp + (size_t)(pp * 32) * K + k0, Bd + pp * 2048);
    }
    __syncthreads();
#pragma unroll
    for (int ks = 0; ks < 2; ++ks) {
      bf16x8 af[4], bfr[4];
#pragma unroll
      for (int i = 0; i < 4; ++i)
        af[i] = *(const bf16x8*)&As[(wm + i * 16 + l16) * 64 +
                                    (((ks * 4 + quad) ^ (l16 & 7)) << 3)];
#pragma unroll
      for (int j = 0; j < 4; ++j)
        bfr[j] = *(const bf16x8*)&Bs[(wn + j * 16 + l16) * 64 +
                                     (((ks * 4 + quad) ^ (l16 & 7)) << 3)];
#pragma unroll
      for (int i = 0; i < 4; ++i)
#pragma unroll
        for (int j = 0; j < 4; ++j)
          acc[i][j] = __builtin_amdgcn_mfma_f32_16x16x32_bf16(af[i], bfr[j], acc[i][j], 0, 0, 0);
    }
  }
  // C row = quad*4+reg, col = l16 (verified mapping)
#pragma unroll
  for (int i = 0; i < 4; ++i)
#pragma unroll
    for (int j = 0; j < 4; ++j) {
      const int col = bn + wn + j * 16 + l16;
      const int row0 = bm + wm + i * 16 + quad * 4;
      if (MODE == 1 && col >= 2048) {
        const int d = col - 2048;
        const int hh = d >> 6, dd = d & 63;
        const int bb = row0 >> 11, ss = row0 & 2047;
        ushort4 pk;
        pk.x = f2bf(acc[i][j][0]); pk.y = f2bf(acc[i][j][1]);
        pk.z = f2bf(acc[i][j][2]); pk.w = f2bf(acc[i][j][3]);
        *(ushort4*)(vt + ((size_t)((bb * NH + hh) * HD + dd)) * SEQ + ss) = pk;
      } else {
#pragma unroll
        for (int r = 0; r < 4; ++r) {
          if (MODE == 1)
            ((bf16_t*)Cout)[(size_t)(row0 + r) * N + col] = f2bf(acc[i][j][r]);
          else
            ((float*)Cout)[(size_t)(row0 + r) * N + col] = acc[i][j][r];
        }
      }
    }
}

// ---------------- flash attention, barrier-free ----------------
// 512 blocks XCD-swizzled; 4 waves x 32q = 128q per block, Q-tiles (p,15-p).
// Waves fully independent: K/V fragments read straight from global (L2-resident
// per XCD thanks to the swizzle); LDS = per-wave P only; no __syncthreads.
// Q pre-scaled by 0.125*log2e => p = exp2(s'), shift cancels in normalization.
#define QSCALE 0.18033688011112042f   // 0.125 * log2(e)
__global__ __launch_bounds__(256, 3) void k_attn(const bf16_t* __restrict__ qkv,
                                                 const bf16_t* __restrict__ vt,
                                                 bf16_t* __restrict__ y) {
  __shared__ __align__(16) short Pb[4][32 * 64];   // per-wave P, granule-XOR
  const int tid = threadIdx.x;
  const int wave = tid >> 6, lane = tid & 63;
  const int quad = lane >> 4, l16 = lane & 15;
  const int l = blockIdx.x;
  const int p = (l >> 3) & 7;                    // pair index 0..7
  const int g = ((l >> 6) << 3) | (l & 7);       // (h,b) group, const per XCD slice
  const int h = g & 15, b = g >> 4;
  const size_t bbase = (size_t)b * SEQ * QKV_W;
  short* Pw = &Pb[wave][0];
  // K fragment base: row s = jn*16+l16, cols ks*32+quad*8
  const bf16_t* kfb = qkv + bbase + (size_t)l16 * QKV_W + DM + h * HD + quad * 8;
  // V fragment base: row d = jn*16+l16, cols kv0+ks*32+quad*8
  const bf16_t* vfb = vt + ((size_t)(b * NH + h) * HD + l16) * SEQ + quad * 8;

  for (int half = 0; half < 2; ++half) {
    const int qt = half ? (15 - p) : p;
    const int qb = qt * 128 + wave * 32;         // wave's first q row
    // load + pre-scale Q fragments: aq[mi][kk]
    bf16x8 aq[2][2];
#pragma unroll
    for (int mi = 0; mi < 2; ++mi)
#pragma unroll
      for (int kk = 0; kk < 2; ++kk) {
        const bf16_t* qp = qkv + bbase + (size_t)(qb + mi * 16 + l16) * QKV_W +
                           h * HD + kk * 32 + quad * 8;
        bf16x8 raw = *(const bf16x8*)qp;
        bf16x8 sc;
#pragma unroll
        for (int e = 0; e < 8; ++e)
          sc[e] = (short)f2bf(bf2f((unsigned short)raw[e]) * QSCALE);
        aq[mi][kk] = sc;
      }
    f32x4 o[2][4];
    float lsum[2][4];
#pragma unroll
    for (int mi = 0; mi < 2; ++mi)
#pragma unroll
      for (int jn = 0; jn < 4; ++jn) o[mi][jn] = f32x4{0.f, 0.f, 0.f, 0.f};
#pragma unroll
    for (int mi = 0; mi < 2; ++mi)
#pragma unroll
      for (int r = 0; r < 4; ++r) lsum[mi][r] = 0.f;

    const int jlim = (qb + 31) >> 6;             // last KV tile with unmasked cols
    for (int j = 0; j <= jlim; ++j) {
      const int kv0 = j * 64;
      const bool needmask = (kv0 + 63 > qb);
      // ---- K fragments from global (L2) ----
      bf16x8 kf[2][4];
#pragma unroll
      for (int ks = 0; ks < 2; ++ks)
#pragma unroll
        for (int jn = 0; jn < 4; ++jn)
          kf[ks][jn] = *(const bf16x8*)(kfb + (size_t)(kv0 + jn * 16) * QKV_W + ks * 32);
      // ---- S = Q K^T ----
      f32x4 sacc[2][4];
#pragma unroll
      for (int jn = 0; jn < 4; ++jn)
#pragma unroll
        for (int mi = 0; mi < 2; ++mi) {
          f32x4 s4 = f32x4{0.f, 0.f, 0.f, 0.f};
          s4 = __builtin_amdgcn_mfma_f32_16x16x32_bf16(aq[mi][0], kf[0][jn], s4, 0, 0, 0);
          s4 = __builtin_amdgcn_mfma_f32_16x16x32_bf16(aq[mi][1], kf[1][jn], s4, 0, 0, 0);
          sacc[mi][jn] = s4;
        }
      // ---- V fragments issued now; latency hidden by exp/P-write below ----
      bf16x8 vf[2][4];
#pragma unroll
      for (int ks = 0; ks < 2; ++ks)
#pragma unroll
        for (int jn = 0; jn < 4; ++jn)
          vf[ks][jn] = *(const bf16x8*)(vfb + (size_t)(jn * 16) * SEQ + kv0 + ks * 32);
      // ---- p = exp2(s'); mask near diagonal; truncating bf16 store ----
#pragma unroll
      for (int mi = 0; mi < 2; ++mi)
#pragma unroll
        for (int r = 0; r < 4; ++r) {
          const int prow = mi * 16 + quad * 4 + r;
          const int qr = qb + prow;
#pragma unroll
          for (int jn = 0; jn < 4; ++jn) {
            float e = __builtin_amdgcn_exp2f(sacc[mi][jn][r]);
            if (needmask) e = (kv0 + jn * 16 + l16 <= qr) ? e : 0.f;
            lsum[mi][r] += e;
            const int pcol = jn * 16 + l16;
            Pw[prow * 64 + ((((pcol >> 3) ^ (prow & 7))) << 3) + (pcol & 7)] =
                (short)(__float_as_uint(e) >> 16);
          }
        }
      // ---- O += P V ----
#pragma unroll
      for (int ks = 0; ks < 2; ++ks) {
        const int gsw = ((ks * 4 + quad) ^ (l16 & 7)) << 3;
        bf16x8 ap0 = *(const bf16x8*)&Pw[l16 * 64 + gsw];
        bf16x8 ap1 = *(const bf16x8*)&Pw[(16 + l16) * 64 + gsw];
#pragma unroll
        for (int jn = 0; jn < 4; ++jn) {
          o[0][jn] = __builtin_amdgcn_mfma_f32_16x16x32_bf16(ap0, vf[ks][jn], o[0][jn], 0, 0, 0);
          o[1][jn] = __builtin_amdgcn_mfma_f32_16x16x32_bf16(ap1, vf[ks][jn], o[1][jn], 0, 0, 0);
        }
      }
    }
    // normalize + write
#pragma unroll
    for (int mi = 0; mi < 2; ++mi)
#pragma unroll
      for (int r = 0; r < 4; ++r) {
        float s = lsum[mi][r];
        s += __shfl_xor(s, 1, 64);
        s += __shfl_xor(s, 2, 64);
        s += __shfl_xor(s, 4, 64);
        s += __shfl_xor(s, 8, 64);
        const float invl = 1.0f / s;
        const int qr = qb + mi * 16 + quad * 4 + r;
        bf16_t* yp = y + ((size_t)b * SEQ + qr) * DM + h * HD;
#pragma unroll
        for (int jn = 0; jn < 4; ++jn)
          yp[jn * 16 + l16] = f2bf(o[mi][jn][r] * invl);
      }
  }
}

extern "C" void kernel_launch(void* const* d_in, const int* in_sizes, int n_in,
                              void* d_out, int out_size, void* d_ws, size_t ws_size,
                              hipStream_t stream) {
  const float* x     = (const float*)d_in[0];
  const float* Wqkv  = (const float*)d_in[1];
  const float* Wproj = (const float*)d_in[2];
  float* out = (float*)d_out;
  char* ws = (char*)d_ws;
  // ws layout (72 MiB):
  bf16_t* qkv = (bf16_t*)(ws);                 // 48 MiB (V third unused)
  bf16_t* Wt1 = (bf16_t*)(ws + 50331648);      // 6 MiB
  bf16_t* Wt2 = (bf16_t*)(ws + 56623104);      // 2 MiB
  bf16_t* xb  = (bf16_t*)(ws + 58720256);      // 16 MiB (dead after GEMM1)
  bf16_t* y   = xb;                            // attn output aliases xb
  // V^T parked in d_out's first 16 MiB; dead before GEMM2 overwrites d_out.
  bf16_t* vt  = (bf16_t*)d_out;

  k_transpose<<<dim3(QKV_W / 32, DM / 32), dim3(32, 8), 0, stream>>>(Wqkv, Wt1, DM, QKV_W);
  k_transpose<<<dim3(DM / 32, DM / 32), dim3(32, 8), 0, stream>>>(Wproj, Wt2, DM, DM);
  k_cvt<<<(BATCH * SEQ * DM) / (4 * 256), 256, 0, stream>>>(x, xb);
  k_gemm<1><<<dim3(QKV_W / 128, (BATCH * SEQ) / 128), 256, 0, stream>>>(
      xb, Wt1, qkv, vt, BATCH * SEQ, QKV_W, DM);
  k_rope<<<(BATCH * SEQ * NH * 32) / 256, 256, 0, stream>>>(qkv);
  k_attn<<<512, 256, 0, stream>>>(qkv, vt, y);
  k_gemm<0><<<dim3(DM / 128, (BATCH * SEQ) / 128), 256, 0, stream>>>(
      y, Wt2, out, nullptr, BATCH * SEQ, DM, DM);
}

// Round 7
// 266.523 us; speedup vs baseline: 1.2423x; 1.2423x over previous
//
#include <hip/hip_runtime.h>

// Causal self-attention fwd: x(4,2048,1024)fp32, W_qkv(1024,3072), W_proj(1024,1024)
// Pipeline: [transpose W->bf16] [x->bf16] [GEMM1 qkv + fused V-transpose] [RoPE q,k]
//           [flash attn] [GEMM2 out]
// R5: attn 32q/wave, Q pre-scaled (exp2), GEMM BK=64 swizzled.  (75 us attn)
// R6 FAILED: per-wave global K/V gathers = latency-bound (151 us). Reverted.
// R7: R5 staged structure, blocks shrunk to 2 waves / 64q: grid 1024 = 4
//     blocks/CU (LDS 40KB exactly fits 4x), 4 independent barrier domains per
//     CU overlap each other's drains. Pairs (p,31-p) of 32 tiles = 33 iters.

#define BATCH 4
#define SEQ   2048
#define DM    1024
#define NH    16
#define HD    64
#define QKV_W 3072

typedef short bf16x8 __attribute__((ext_vector_type(8)));
typedef float f32x4  __attribute__((ext_vector_type(4)));
typedef unsigned short bf16_t;

__device__ __forceinline__ unsigned short f2bf(float f) {
  unsigned u = __float_as_uint(f);
  u += 0x7fffu + ((u >> 16) & 1u);   // round-to-nearest-even
  return (unsigned short)(u >> 16);
}
__device__ __forceinline__ float bf2f(unsigned short s) {
  return __uint_as_float((unsigned)s << 16);
}
// async global->LDS, 16B per lane; LDS dest is wave-uniform base + lane*16
__device__ __forceinline__ void gld16(const void* g, void* l) {
  __builtin_amdgcn_global_load_lds(
      (const __attribute__((address_space(1))) unsigned int*)g,
      (__attribute__((address_space(3))) unsigned int*)l, 16, 0, 0);
}

// ---------------- W[K][N] fp32 -> Wt[N][K] bf16 ----------------
__global__ __launch_bounds__(256) void k_transpose(const float* __restrict__ W,
                                                   bf16_t* __restrict__ Wt,
                                                   int K, int N) {
  __shared__ float tile[32][33];
  const int tx = threadIdx.x, ty = threadIdx.y;   // (32,8)
  const int n0 = blockIdx.x * 32, k0 = blockIdx.y * 32;
#pragma unroll
  for (int j = 0; j < 4; ++j)
    tile[ty + j * 8][tx] = W[(size_t)(k0 + ty + j * 8) * N + n0 + tx];
  __syncthreads();
#pragma unroll
  for (int j = 0; j < 4; ++j)
    Wt[(size_t)(n0 + ty + j * 8) * K + k0 + tx] = f2bf(tile[tx][ty + j * 8]);
}

// ---------------- fp32 -> bf16 elementwise ----------------
__global__ __launch_bounds__(256) void k_cvt(const float* __restrict__ x,
                                             bf16_t* __restrict__ xb) {
  const int i = (blockIdx.x * 256 + threadIdx.x) * 4;
  float4 v = *(const float4*)(x + i);
  unsigned lo = (unsigned)f2bf(v.x) | ((unsigned)f2bf(v.y) << 16);
  unsigned hi = (unsigned)f2bf(v.z) | ((unsigned)f2bf(v.w) << 16);
  *(uint2*)(xb + i) = make_uint2(lo, hi);
}

// ---------------- RoPE in place on q,k sections of qkv ----------------
__global__ __launch_bounds__(256) void k_rope(bf16_t* __restrict__ qkv) {
  const int t = blockIdx.x * 256 + threadIdx.x;
  const int i = t & 31;            // freq index 0..31
  const int h = (t >> 5) & 15;     // head
  const int s = (t >> 9) & 2047;   // position
  const int b = t >> 20;
  const float inv = __expf((float)i * -0.28782313662425575f); // -ln(10000)/32
  float sn, cs;
  sincosf((float)s * inv, &sn, &cs);
  size_t base = ((size_t)(b * SEQ + s)) * QKV_W + h * HD + 2 * i;
#pragma unroll
  for (int part = 0; part < 2; ++part) {      // q then k
    unsigned u = *(unsigned*)(qkv + base + part * DM);
    float e = bf2f((unsigned short)(u & 0xffffu));
    float o = bf2f((unsigned short)(u >> 16));
    unsigned short e2 = f2bf(e * cs - o * sn);
    unsigned short o2 = f2bf(e * sn + o * cs);
    *(unsigned*)(qkv + base + part * DM) = (unsigned)e2 | ((unsigned)o2 << 16);
  }
}

// ---------------- bf16 GEMM: C = A[M][K] * Bt[N][K]^T ----------------
// 128x128 tile, BK=64 (16 iters @ K=1024), XOR-swizzled [128][64] LDS.
// MODE 0: fp32 C. MODE 1: qkv epilogue — cols<2048 (Q,K) bf16 row-major;
// cols>=2048 (V) -> vt[b][h][d][s] packed ushort4.
template<int MODE>
__global__ __launch_bounds__(256) void k_gemm(const bf16_t* __restrict__ A,
                                              const bf16_t* __restrict__ Bt,
                                              void* __restrict__ Cout,
                                              bf16_t* __restrict__ vt,
                                              int M, int N, int K) {
  __shared__ __align__(16) short As[128 * 64];
  __shared__ __align__(16) short Bs[128 * 64];
  const int tid = threadIdx.x;
  const int wave = tid >> 6, lane = tid & 63;
  const int quad = lane >> 4, l16 = lane & 15;
  const int wm = (wave >> 1) * 64, wn = (wave & 1) * 64;
  const int bm = blockIdx.y * 128, bn = blockIdx.x * 128;

  f32x4 acc[4][4];
#pragma unroll
  for (int i = 0; i < 4; ++i)
#pragma unroll
    for (int j = 0; j < 4; ++j) acc[i][j] = f32x4{0.f, 0.f, 0.f, 0.f};

  const int srow = tid >> 3;                       // 0..31
  const int sg   = (tid & 7) ^ (srow & 7);         // swizzled source granule
  const bf16_t* Ap = A  + (size_t)(bm + srow) * K + sg * 8;
  const bf16_t* Bp = Bt + (size_t)(bn + srow) * K + sg * 8;
  short* Ad = As + tid * 8;
  short* Bd = Bs + tid * 8;

  for (int k0 = 0; k0 < K; k0 += 64) {
    __syncthreads();
#pragma unroll
    for (int pp = 0; pp < 4; ++pp) {
      gld16(Ap + (size_t)(pp * 32) * K + k0, Ad + pp * 2048);
      gld16(Bp + (size_t)(pp * 32) * K + k0, Bd + pp * 2048);
    }
    __syncthreads();
#pragma unroll
    for (int ks = 0; ks < 2; ++ks) {
      bf16x8 af[4], bfr[4];
#pragma unroll
      for (int i = 0; i < 4; ++i)
        af[i] = *(const bf16x8*)&As[(wm + i * 16 + l16) * 64 +
                                    (((ks * 4 + quad) ^ (l16 & 7)) << 3)];
#pragma unroll
      for (int j = 0; j < 4; ++j)
        bfr[j] = *(const bf16x8*)&Bs[(wn + j * 16 + l16) * 64 +
                                     (((ks * 4 + quad) ^ (l16 & 7)) << 3)];
#pragma unroll
      for (int i = 0; i < 4; ++i)
#pragma unroll
        for (int j = 0; j < 4; ++j)
          acc[i][j] = __builtin_amdgcn_mfma_f32_16x16x32_bf16(af[i], bfr[j], acc[i][j], 0, 0, 0);
    }
  }
  // C row = quad*4+reg, col = l16 (verified mapping)
#pragma unroll
  for (int i = 0; i < 4; ++i)
#pragma unroll
    for (int j = 0; j < 4; ++j) {
      const int col = bn + wn + j * 16 + l16;
      const int row0 = bm + wm + i * 16 + quad * 4;
      if (MODE == 1 && col >= 2048) {
        const int d = col - 2048;
        const int hh = d >> 6, dd = d & 63;
        const int bb = row0 >> 11, ss = row0 & 2047;
        ushort4 pk;
        pk.x = f2bf(acc[i][j][0]); pk.y = f2bf(acc[i][j][1]);
        pk.z = f2bf(acc[i][j][2]); pk.w = f2bf(acc[i][j][3]);
        *(ushort4*)(vt + ((size_t)((bb * NH + hh) * HD + dd)) * SEQ + ss) = pk;
      } else {
#pragma unroll
        for (int r = 0; r < 4; ++r) {
          if (MODE == 1)
            ((bf16_t*)Cout)[(size_t)(row0 + r) * N + col] = f2bf(acc[i][j][r]);
          else
            ((float*)Cout)[(size_t)(row0 + r) * N + col] = acc[i][j][r];
        }
      }
    }
}

// ---------------- flash attention ----------------
// 1024 blocks x 128 threads (2 waves x 32q = 64q). XCD-swizzled: 16 blocks of
// each (h,b) share an XCD slice. Q-tile pairs (p,31-p) of 32 => uniform 33
// iters. KV double-buffer + cross-iter prefetch, 1 barrier/iter. LDS = 40KB
// -> exactly 4 blocks/CU = 4 independent barrier domains hiding each other.
// Q pre-scaled by 0.125*log2e => p = exp2(s'), shift cancels in normalization.
#define QSCALE 0.18033688011112042f   // 0.125 * log2(e)
__global__ __launch_bounds__(128, 2) void k_attn(const bf16_t* __restrict__ qkv,
                                                 const bf16_t* __restrict__ vt,
                                                 bf16_t* __restrict__ y) {
  __shared__ __align__(16) short KV[2][4][64 * 32];  // [buf][K0,K1,V0,V1] 32KB
  __shared__ __align__(16) short Pb[2][32 * 64];     // per-wave P, granule-XOR 8KB
  const int tid = threadIdx.x;         // 0..127
  const int wave = tid >> 6, lane = tid & 63;
  const int quad = lane >> 4, l16 = lane & 15;
  const int l = blockIdx.x;
  const int p = (l >> 3) & 15;                   // pair index 0..15
  const int g = ((l >> 7) << 3) | (l & 7);       // (h,b) group, const per XCD slice
  const int h = g & 15, b = g >> 4;
  const size_t bbase = (size_t)b * SEQ * QKV_W;
  short* Pw = &Pb[wave][0];
  const int srow = tid >> 2;            // staging row 0..31
  const int sc8  = (tid & 3) * 8;       // staging col 0,8,16,24
  const bf16_t* kbase = qkv + bbase + (size_t)srow * QKV_W + DM + h * HD + sc8;
  const bf16_t* vbase = vt + ((size_t)(b * NH + h) * HD + srow) * SEQ + sc8;

  // 8 x 2KB staging calls per iter (128 threads x 16B); rows split 0-31 / 32-63
#define ISSUE(kv0, buf)                                                        \
  do {                                                                         \
    gld16(kbase + (size_t)(kv0) * QKV_W,           &KV[buf][0][tid * 8]);       \
    gld16(kbase + (size_t)((kv0) + 32) * QKV_W,    &KV[buf][0][(128 + tid) * 8]);\
    gld16(kbase + (size_t)(kv0) * QKV_W + 32,      &KV[buf][1][tid * 8]);       \
    gld16(kbase + (size_t)((kv0) + 32) * QKV_W + 32, &KV[buf][1][(128 + tid) * 8]);\
    gld16(vbase + (kv0),                           &KV[buf][2][tid * 8]);       \
    gld16(vbase + (size_t)32 * SEQ + (kv0),        &KV[buf][2][(128 + tid) * 8]);\
    gld16(vbase + (kv0) + 32,                      &KV[buf][3][tid * 8]);       \
    gld16(vbase + (size_t)32 * SEQ + (kv0) + 32,   &KV[buf][3][(128 + tid) * 8]);\
  } while (0)

  int bufp = 0;
  ISSUE(0, 0);
  for (int half = 0; half < 2; ++half) {
    const int qt = half ? (31 - p) : p;            // 64-row Q tile index 0..31
    const int qb = qt * 64 + wave * 32;            // wave's first q row
    // load + pre-scale Q fragments: aq[mi][kk]
    bf16x8 aq[2][2];
#pragma unroll
    for (int mi = 0; mi < 2; ++mi)
#pragma unroll
      for (int kk = 0; kk < 2; ++kk) {
        const bf16_t* qp = qkv + bbase + (size_t)(qb + mi * 16 + l16) * QKV_W +
                           h * HD + kk * 32 + quad * 8;
        bf16x8 raw = *(const bf16x8*)qp;
        bf16x8 sc;
#pragma unroll
        for (int e = 0; e < 8; ++e)
          sc[e] = (short)f2bf(bf2f((unsigned short)raw[e]) * QSCALE);
        aq[mi][kk] = sc;
      }
    f32x4 o[2][4];
    float lsum[2][4];
#pragma unroll
    for (int mi = 0; mi < 2; ++mi)
#pragma unroll
      for (int jn = 0; jn < 4; ++jn) o[mi][jn] = f32x4{0.f, 0.f, 0.f, 0.f};
#pragma unroll
    for (int mi = 0; mi < 2; ++mi)
#pragma unroll
      for (int r = 0; r < 4; ++r) lsum[mi][r] = 0.f;

    for (int j = 0; j <= qt; ++j) {
      const int kv0 = j * 64;
      __syncthreads();   // drains this buf's loads; WAR-protects prefetch target
      if (j < qt)            ISSUE(kv0 + 64, bufp ^ 1);
      else if (half == 0)    ISSUE(0, bufp ^ 1);
      const bool needmask = (kv0 + 63 > qb);
      const short* Kc0 = &KV[bufp][0][0];
      const short* Kc1 = &KV[bufp][1][0];
      const short* Vc0 = &KV[bufp][2][0];
      const short* Vc1 = &KV[bufp][3][0];

      f32x4 sacc[2][4];
#pragma unroll
      for (int jn = 0; jn < 4; ++jn) {
        bf16x8 bk0 = *(const bf16x8*)&Kc0[(jn * 16 + l16) * 32 + quad * 8];
        bf16x8 bk1 = *(const bf16x8*)&Kc1[(jn * 16 + l16) * 32 + quad * 8];
#pragma unroll
        for (int mi = 0; mi < 2; ++mi) {
          f32x4 s4 = f32x4{0.f, 0.f, 0.f, 0.f};
          s4 = __builtin_amdgcn_mfma_f32_16x16x32_bf16(aq[mi][0], bk0, s4, 0, 0, 0);
          s4 = __builtin_amdgcn_mfma_f32_16x16x32_bf16(aq[mi][1], bk1, s4, 0, 0, 0);
          sacc[mi][jn] = s4;
        }
      }
      // p = exp2(s'); mask near diagonal; truncating bf16 store
#pragma unroll
      for (int mi = 0; mi < 2; ++mi)
#pragma unroll
        for (int r = 0; r < 4; ++r) {
          const int prow = mi * 16 + quad * 4 + r;
          const int qr = qb + prow;
#pragma unroll
          for (int jn = 0; jn < 4; ++jn) {
            float e = __builtin_amdgcn_exp2f(sacc[mi][jn][r]);
            if (needmask) e = (kv0 + jn * 16 + l16 <= qr) ? e : 0.f;
            lsum[mi][r] += e;
            const int pcol = jn * 16 + l16;
            Pw[prow * 64 + ((((pcol >> 3) ^ (prow & 7))) << 3) + (pcol & 7)] =
                (short)(__float_as_uint(e) >> 16);
          }
        }
      // O += P V  (P A-frags from per-wave LDS; V frags shared across mi)
#pragma unroll
      for (int ks = 0; ks < 2; ++ks) {
        const int gsw = ((ks * 4 + quad) ^ (l16 & 7)) << 3;
        bf16x8 ap0 = *(const bf16x8*)&Pw[l16 * 64 + gsw];
        bf16x8 ap1 = *(const bf16x8*)&Pw[(16 + l16) * 64 + gsw];
        const short* Vc = ks ? Vc1 : Vc0;
#pragma unroll
        for (int jn = 0; jn < 4; ++jn) {
          bf16x8 bv = *(const bf16x8*)&Vc[(jn * 16 + l16) * 32 + quad * 8];
          o[0][jn] = __builtin_amdgcn_mfma_f32_16x16x32_bf16(ap0, bv, o[0][jn], 0, 0, 0);
          o[1][jn] = __builtin_amdgcn_mfma_f32_16x16x32_bf16(ap1, bv, o[1][jn], 0, 0, 0);
        }
      }
      bufp ^= 1;
    }
    // normalize + write
#pragma unroll
    for (int mi = 0; mi < 2; ++mi)
#pragma unroll
      for (int r = 0; r < 4; ++r) {
        float s = lsum[mi][r];
        s += __shfl_xor(s, 1, 64);
        s += __shfl_xor(s, 2, 64);
        s += __shfl_xor(s, 4, 64);
        s += __shfl_xor(s, 8, 64);
        const float invl = 1.0f / s;
        const int qr = qb + mi * 16 + quad * 4 + r;
        bf16_t* yp = y + ((size_t)b * SEQ + qr) * DM + h * HD;
#pragma unroll
        for (int jn = 0; jn < 4; ++jn)
          yp[jn * 16 + l16] = f2bf(o[mi][jn][r] * invl);
      }
  }
#undef ISSUE
}

extern "C" void kernel_launch(void* const* d_in, const int* in_sizes, int n_in,
                              void* d_out, int out_size, void* d_ws, size_t ws_size,
                              hipStream_t stream) {
  const float* x     = (const float*)d_in[0];
  const float* Wqkv  = (const float*)d_in[1];
  const float* Wproj = (const float*)d_in[2];
  float* out = (float*)d_out;
  char* ws = (char*)d_ws;
  // ws layout (72 MiB):
  bf16_t* qkv = (bf16_t*)(ws);                 // 48 MiB (V third unused)
  bf16_t* Wt1 = (bf16_t*)(ws + 50331648);      // 6 MiB
  bf16_t* Wt2 = (bf16_t*)(ws + 56623104);      // 2 MiB
  bf16_t* xb  = (bf16_t*)(ws + 58720256);      // 16 MiB (dead after GEMM1)
  bf16_t* y   = xb;                            // attn output aliases xb
  // V^T parked in d_out's first 16 MiB; dead before GEMM2 overwrites d_out.
  bf16_t* vt  = (bf16_t*)d_out;

  k_transpose<<<dim3(QKV_W / 32, DM / 32), dim3(32, 8), 0, stream>>>(Wqkv, Wt1, DM, QKV_W);
  k_transpose<<<dim3(DM / 32, DM / 32), dim3(32, 8), 0, stream>>>(Wproj, Wt2, DM, DM);
  k_cvt<<<(BATCH * SEQ * DM) / (4 * 256), 256, 0, stream>>>(x, xb);
  k_gemm<1><<<dim3(QKV_W / 128, (BATCH * SEQ) / 128), 256, 0, stream>>>(
      xb, Wt1, qkv, vt, BATCH * SEQ, QKV_W, DM);
  k_rope<<<(BATCH * SEQ * NH * 32) / 256, 256, 0, stream>>>(qkv);
  k_attn<<<1024, 128, 0, stream>>>(qkv, vt, y);
  k_gemm<0><<<dim3(DM / 128, (BATCH * SEQ) / 128), 256, 0, stream>>>(
      y, Wt2, out, nullptr, BATCH * SEQ, DM, DM);
}